// Round 3
// baseline (450.535 us; speedup 1.0000x reference)
//
#include <hip/hip_runtime.h>

// MomentumSSM B=2, L=4096, D=512, N=16, R=32, P=64 — chunk-parallel scan, NCH=128.
//
// ws layout (floats):
//   proj[b][l][p]   2 MB   (p: 0..31 dt_in, 32..47 B, 48..63 C)
//   dt  [b][l][d]  16 MB
//   hh/vh/cv [b][c][d][n]  3 x 8.4 MB   (chunk-local h,v,cv; fixup overwrites hh/vh with H0/V0)
//   sdt [b][c][d]   0.5 MB (sum of dt over chunk; Pa[n] = exp2(sdt*A2[n]) recomputed in fixup)
//
// v_t = beta*v + alpha*inp ; h_t = a_t*h + v ; a_t = exp(dt*A_n)
// chunk map: h_end = Pa*H0 + cv*V0 + hhat ; v_end = beta^LCH*V0 + vhat

#define D_IN 512
#define D_ST 16
#define DTR  32
#define BSZ  2
#define LSEQ 4096
#define PDIM 64
#define NCH  128
#define LCH  (LSEQ / NCH)  // 32
#define LOG2E 1.44269504f

// ---------------- proj = x @ W_xproj^T : 64x64 tile, 4x4/thread, no LDS ------
__global__ __launch_bounds__(256) void k_proj(const float* __restrict__ x,
                                              const float* __restrict__ W,
                                              float* __restrict__ proj) {
  const int row0 = blockIdx.x * 64;
  const int tx = threadIdx.x & 15;   // p-quad
  const int ty = threadIdx.x >> 4;   // row-quad
  const float* xr[4];
  const float* wr[4];
#pragma unroll
  for (int i = 0; i < 4; ++i) {
    xr[i] = x + (size_t)(row0 + ty * 4 + i) * D_IN;
    wr[i] = W + (size_t)(tx * 4 + i) * D_IN;
  }
  float acc[4][4] = {};
#pragma unroll 2
  for (int k = 0; k < D_IN; k += 4) {
    float4 xv[4], wv[4];
#pragma unroll
    for (int i = 0; i < 4; ++i) xv[i] = *(const float4*)(xr[i] + k);
#pragma unroll
    for (int j = 0; j < 4; ++j) wv[j] = *(const float4*)(wr[j] + k);
#pragma unroll
    for (int i = 0; i < 4; ++i)
#pragma unroll
      for (int j = 0; j < 4; ++j)
        acc[i][j] += xv[i].x * wv[j].x + xv[i].y * wv[j].y +
                     xv[i].z * wv[j].z + xv[i].w * wv[j].w;
  }
#pragma unroll
  for (int i = 0; i < 4; ++i)
    *(float4*)(proj + (size_t)(row0 + ty * 4 + i) * PDIM + tx * 4) =
        make_float4(acc[i][0], acc[i][1], acc[i][2], acc[i][3]);
}

// ---------------- dt = softplus(proj[:, :32] @ W_dt^T + b_dt) ----------------
__global__ __launch_bounds__(256) void k_dt(const float* __restrict__ proj,
                                            const float* __restrict__ W_dt,
                                            const float* __restrict__ b_dt,
                                            float* __restrict__ dt) {
  const int r0 = blockIdx.x * 8;
  const int d = blockIdx.y * 256 + threadIdx.x;
  float w[DTR];
  const float4* wp = (const float4*)(W_dt + (size_t)d * DTR);
#pragma unroll
  for (int i = 0; i < 8; ++i) ((float4*)w)[i] = wp[i];
  const float bb = b_dt[d];
#pragma unroll
  for (int r = 0; r < 8; ++r) {
    const float* pr = proj + (size_t)(r0 + r) * PDIM;  // wave-uniform
    float a0 = bb, a1 = 0.f, a2 = 0.f, a3 = 0.f;
#pragma unroll
    for (int k = 0; k < DTR; k += 4) {
      a0 = fmaf(pr[k + 0], w[k + 0], a0);
      a1 = fmaf(pr[k + 1], w[k + 1], a1);
      a2 = fmaf(pr[k + 2], w[k + 2], a2);
      a3 = fmaf(pr[k + 3], w[k + 3], a3);
    }
    float acc = (a0 + a1) + (a2 + a3);
    float sp = (acc > 20.f) ? acc : log1pf(__expf(acc));
    dt[(size_t)(r0 + r) * D_IN + d] = sp;
  }
}

// ---------------- pass 1: zero-init chunk run, emit {hhat,vhat,cv,sumdt} -----
__global__ __launch_bounds__(256) void k_scan1(const float* __restrict__ dt,
                                               const float* __restrict__ x,
                                               const float* __restrict__ proj,
                                               const float* __restrict__ A_log,
                                               const float* __restrict__ alpha_p,
                                               const float* __restrict__ beta_p,
                                               float* __restrict__ hh,
                                               float* __restrict__ vh,
                                               float* __restrict__ cvv,
                                               float* __restrict__ sdt) {
  const int c = blockIdx.x, b = blockIdx.z;
  const int d = blockIdx.y * 256 + threadIdx.x;
  const float alpha = alpha_p[0];
  const float beta = 1.f / (1.f + __expf(-beta_p[0]));
  float A2[D_ST];
  {
    const float4* ap = (const float4*)(A_log + (size_t)d * D_ST);
#pragma unroll
    for (int i = 0; i < 4; ++i) {
      float4 a4 = ap[i];
      A2[4 * i + 0] = -__expf(a4.x) * LOG2E;
      A2[4 * i + 1] = -__expf(a4.y) * LOG2E;
      A2[4 * i + 2] = -__expf(a4.z) * LOG2E;
      A2[4 * i + 3] = -__expf(a4.w) * LOG2E;
    }
  }
  float h[16] = {}, v[16] = {}, cv[16] = {};
  float bpow = 1.f, sd = 0.f;

  const int t0 = c * LCH;
  const float* dtp = dt + (size_t)b * LSEQ * D_IN + d;
  const float* xp = x + (size_t)b * LSEQ * D_IN + d;
  const float* bcp = proj + (size_t)b * LSEQ * PDIM + DTR;

  float dpre[2], xpre[2];
  float4 Bpre[2][4];
#pragma unroll
  for (int jj = 0; jj < 2; ++jj) {
    const size_t t = t0 + jj;
    dpre[jj] = dtp[t * D_IN];
    xpre[jj] = xp[t * D_IN];
#pragma unroll
    for (int i = 0; i < 4; ++i) Bpre[jj][i] = *(const float4*)(bcp + t * PDIM + 4 * i);
  }

  for (int j = 0; j < LCH; ++j) {
    const int s = j & 1;
    const float dcur = dpre[s], xcur = xpre[s];
    float4 Bc[4];
#pragma unroll
    for (int i = 0; i < 4; ++i) Bc[i] = Bpre[s][i];
    const size_t tn = t0 + ((j + 2) & (LCH - 1));  // wraps; last 2 prefetches unused
    dpre[s] = dtp[tn * D_IN];
    xpre[s] = xp[tn * D_IN];
#pragma unroll
    for (int i = 0; i < 4; ++i) Bpre[s][i] = *(const float4*)(bcp + tn * PDIM + 4 * i);

    sd += dcur;
    bpow *= beta;
    const float u = alpha * dcur * xcur;
    const float* Bf = (const float*)Bc;
#pragma unroll
    for (int n = 0; n < 16; ++n) {
      float a = exp2f(dcur * A2[n]);
      v[n] = fmaf(beta, v[n], u * Bf[n]);
      h[n] = fmaf(a, h[n], v[n]);
      cv[n] = fmaf(a, cv[n], bpow);
    }
  }

  const size_t base = ((size_t)(b * NCH + c) * D_IN + d) * D_ST;
#pragma unroll
  for (int i = 0; i < 4; ++i) {
    *(float4*)(hh + base + 4 * i) = ((float4*)h)[i];
    *(float4*)(vh + base + 4 * i) = ((float4*)v)[i];
    *(float4*)(cvv + base + 4 * i) = ((float4*)cv)[i];
  }
  sdt[(size_t)(b * NCH + c) * D_IN + d] = sd;
}

// ---------------- fixup: scan over 128 chunks; writes H0/V0 in-place ---------
__global__ __launch_bounds__(256) void k_fix(float* __restrict__ hh,
                                             float* __restrict__ vh,
                                             const float* __restrict__ cvv,
                                             const float* __restrict__ sdt,
                                             const float* __restrict__ A_log,
                                             const float* __restrict__ beta_p) {
  const int g = blockIdx.x * 256 + threadIdx.x;  // (b, dn)
  const int b = g >> 13;
  const int dn = g & 8191;
  const float beta = 1.f / (1.f + __expf(-beta_p[0]));
  const float A2 = -__expf(A_log[dn]) * LOG2E;
  float bL = beta;
#pragma unroll
  for (int i = 0; i < 5; ++i) bL *= bL;  // beta^32

  float H = 0.f, V = 0.f;
  size_t idx = (size_t)b * NCH * (D_IN * D_ST) + dn;
  size_t sidx = (size_t)b * NCH * D_IN + (dn >> 4);
  float hhv = hh[idx], vhv = vh[idx], cvn = cvv[idx], sd = sdt[sidx];
  for (int c = 0; c < NCH; ++c) {
    const int cn = (c + 1 < NCH) ? c + 1 : c;
    const size_t idn = ((size_t)b * NCH + cn) * (D_IN * D_ST) + dn;
    const size_t sdn = ((size_t)b * NCH + cn) * D_IN + (dn >> 4);
    float hh2 = hh[idn], vh2 = vh[idn], cv2 = cvv[idn], sd2 = sdt[sdn];
    hh[idx] = H;  // H0 for chunk c (in-place, after reads)
    vh[idx] = V;
    const float Pa = exp2f(sd * A2);
    const float Hn = fmaf(Pa, H, fmaf(cvn, V, hhv));
    V = fmaf(bL, V, vhv);
    H = Hn;
    hhv = hh2; vhv = vh2; cvn = cv2; sd = sd2;
    idx = idn;
  }
}

// ---------------- pass 2: correct-init chunk run, emit y ---------------------
__global__ __launch_bounds__(256) void k_scan2(const float* __restrict__ dt,
                                               const float* __restrict__ x,
                                               const float* __restrict__ proj,
                                               const float* __restrict__ A_log,
                                               const float* __restrict__ D_param,
                                               const float* __restrict__ alpha_p,
                                               const float* __restrict__ beta_p,
                                               const float* __restrict__ hh,
                                               const float* __restrict__ vh,
                                               float* __restrict__ out) {
  const int c = blockIdx.x, b = blockIdx.z;
  const int d = blockIdx.y * 256 + threadIdx.x;
  const float alpha = alpha_p[0];
  const float beta = 1.f / (1.f + __expf(-beta_p[0]));
  const float Dv = D_param[d];
  float A2[D_ST];
  {
    const float4* ap = (const float4*)(A_log + (size_t)d * D_ST);
#pragma unroll
    for (int i = 0; i < 4; ++i) {
      float4 a4 = ap[i];
      A2[4 * i + 0] = -__expf(a4.x) * LOG2E;
      A2[4 * i + 1] = -__expf(a4.y) * LOG2E;
      A2[4 * i + 2] = -__expf(a4.z) * LOG2E;
      A2[4 * i + 3] = -__expf(a4.w) * LOG2E;
    }
  }
  const size_t ibase = ((size_t)(b * NCH + c) * D_IN + d) * D_ST;
  float h[16], v[16];
#pragma unroll
  for (int i = 0; i < 4; ++i) {
    ((float4*)h)[i] = *(const float4*)(hh + ibase + 4 * i);
    ((float4*)v)[i] = *(const float4*)(vh + ibase + 4 * i);
  }

  const int t0 = c * LCH;
  const float* dtp = dt + (size_t)b * LSEQ * D_IN + d;
  const float* xp = x + (size_t)b * LSEQ * D_IN + d;
  const float* bcp = proj + (size_t)b * LSEQ * PDIM + DTR;  // B +0..15, C +16..31
  float* op = out + (size_t)b * LSEQ * D_IN + d;

  float dpre[2], xpre[2];
  float4 BCpre[2][8];
#pragma unroll
  for (int jj = 0; jj < 2; ++jj) {
    const size_t t = t0 + jj;
    dpre[jj] = dtp[t * D_IN];
    xpre[jj] = xp[t * D_IN];
#pragma unroll
    for (int i = 0; i < 8; ++i) BCpre[jj][i] = *(const float4*)(bcp + t * PDIM + 4 * i);
  }

  for (int j = 0; j < LCH; ++j) {
    const int s = j & 1;
    const float dcur = dpre[s], xcur = xpre[s];
    float4 BCc[8];
#pragma unroll
    for (int i = 0; i < 8; ++i) BCc[i] = BCpre[s][i];
    const size_t tn = t0 + ((j + 2) & (LCH - 1));
    dpre[s] = dtp[tn * D_IN];
    xpre[s] = xp[tn * D_IN];
#pragma unroll
    for (int i = 0; i < 8; ++i) BCpre[s][i] = *(const float4*)(bcp + tn * PDIM + 4 * i);

    const float u = alpha * dcur * xcur;
    const float* Bf = (const float*)BCc;  // [0:16)=B, [16:32)=C
    float y0 = 0.f, y1 = 0.f, y2 = 0.f, y3 = 0.f;
#pragma unroll
    for (int n = 0; n < 16; ++n) {
      float a = exp2f(dcur * A2[n]);
      v[n] = fmaf(beta, v[n], u * Bf[n]);
      h[n] = fmaf(a, h[n], v[n]);
      float hc = h[n] * Bf[16 + n];
      if ((n & 3) == 0) y0 += hc;
      else if ((n & 3) == 1) y1 += hc;
      else if ((n & 3) == 2) y2 += hc;
      else y3 += hc;
    }
    op[(size_t)(t0 + j) * D_IN] = (y0 + y1) + (y2 + y3) + Dv * xcur;
  }
}

extern "C" void kernel_launch(void* const* d_in, const int* in_sizes, int n_in,
                              void* d_out, int out_size, void* d_ws, size_t ws_size,
                              hipStream_t stream) {
  const float* x = (const float*)d_in[0];
  const float* A_log = (const float*)d_in[1];
  const float* D_param = (const float*)d_in[2];
  const float* W_xproj = (const float*)d_in[3];
  const float* W_dt = (const float*)d_in[4];
  const float* b_dt = (const float*)d_in[5];
  const float* alpha = (const float*)d_in[6];
  const float* beta_logit = (const float*)d_in[7];
  float* out = (float*)d_out;

  float* ws = (float*)d_ws;
  float* proj = ws;                                   // 524288
  float* dt = proj + (size_t)BSZ * LSEQ * PDIM;       // 4194304
  float* hh = dt + (size_t)BSZ * LSEQ * D_IN;         // 2097152
  float* vh = hh + (size_t)BSZ * NCH * D_IN * D_ST;   // 2097152
  float* cvv = vh + (size_t)BSZ * NCH * D_IN * D_ST;  // 2097152
  float* sdt = cvv + (size_t)BSZ * NCH * D_IN * D_ST; // 131072  (total 44.6 MB)

  k_proj<<<dim3(BSZ * LSEQ / 64), dim3(256), 0, stream>>>(x, W_xproj, proj);
  k_dt<<<dim3(BSZ * LSEQ / 8, D_IN / 256), dim3(256), 0, stream>>>(proj, W_dt, b_dt, dt);
  k_scan1<<<dim3(NCH, D_IN / 256, BSZ), dim3(256), 0, stream>>>(
      dt, x, proj, A_log, alpha, beta_logit, hh, vh, cvv, sdt);
  k_fix<<<dim3(BSZ * D_IN * D_ST / 256), dim3(256), 0, stream>>>(hh, vh, cvv, sdt, A_log,
                                                                 beta_logit);
  k_scan2<<<dim3(NCH, D_IN / 256, BSZ), dim3(256), 0, stream>>>(
      dt, x, proj, A_log, D_param, alpha, beta_logit, hh, vh, out);
}

// Round 4
// 253.380 us; speedup vs baseline: 1.7781x; 1.7781x over previous
//
#include <hip/hip_runtime.h>

// MomentumSSM B=2, L=4096, D=512, N=16, R=32, P=64 — chunk-parallel scan, NCH=128.
// R4: scans use ONLY statically-indexed registers (R3's s=j&1 prefetch arrays
// spilled to scratch: 573 MB writes). k_fix: 256x64 blocks, group-4 lookahead.
//
// ws layout (floats):
//   proj[b][l][p]   2 MB   (p: 0..31 dt_in, 32..47 B, 48..63 C)
//   dt  [b][l][d]  16 MB
//   hh/vh/cv [b][c][d][n]  3 x 8.4 MB  (fixup overwrites hh/vh with H0/V0 in place)
//   sdt [b][c][d]   0.5 MB (Pa[n] recomputed as exp2(sdt*A2[n]))
//
// v_t = beta*v + alpha*inp ; h_t = a_t*h + v ; a_t = exp(dt*A_n)
// chunk map: h_end = Pa*H0 + cv*V0 + hhat ; v_end = beta^LCH*V0 + vhat

#define D_IN 512
#define D_ST 16
#define DTR  32
#define BSZ  2
#define LSEQ 4096
#define PDIM 64
#define NCH  128
#define LCH  (LSEQ / NCH)  // 32
#define LOG2E 1.44269504f

// ---------------- proj = x @ W_xproj^T : 64x64 tile, 4x4/thread, no LDS ------
__global__ __launch_bounds__(256) void k_proj(const float* __restrict__ x,
                                              const float* __restrict__ W,
                                              float* __restrict__ proj) {
  const int row0 = blockIdx.x * 64;
  const int tx = threadIdx.x & 15;   // p-quad
  const int ty = threadIdx.x >> 4;   // row-quad
  const float* xr[4];
  const float* wr[4];
#pragma unroll
  for (int i = 0; i < 4; ++i) {
    xr[i] = x + (size_t)(row0 + ty * 4 + i) * D_IN;
    wr[i] = W + (size_t)(tx * 4 + i) * D_IN;
  }
  float acc[4][4] = {};
#pragma unroll 2
  for (int k = 0; k < D_IN; k += 4) {
    float4 xv[4], wv[4];
#pragma unroll
    for (int i = 0; i < 4; ++i) xv[i] = *(const float4*)(xr[i] + k);
#pragma unroll
    for (int j = 0; j < 4; ++j) wv[j] = *(const float4*)(wr[j] + k);
#pragma unroll
    for (int i = 0; i < 4; ++i)
#pragma unroll
      for (int j = 0; j < 4; ++j)
        acc[i][j] += xv[i].x * wv[j].x + xv[i].y * wv[j].y +
                     xv[i].z * wv[j].z + xv[i].w * wv[j].w;
  }
#pragma unroll
  for (int i = 0; i < 4; ++i)
    *(float4*)(proj + (size_t)(row0 + ty * 4 + i) * PDIM + tx * 4) =
        make_float4(acc[i][0], acc[i][1], acc[i][2], acc[i][3]);
}

// ---------------- dt = softplus(proj[:, :32] @ W_dt^T + b_dt) ----------------
__global__ __launch_bounds__(256) void k_dt(const float* __restrict__ proj,
                                            const float* __restrict__ W_dt,
                                            const float* __restrict__ b_dt,
                                            float* __restrict__ dt) {
  const int r0 = blockIdx.x * 8;
  const int d = blockIdx.y * 256 + threadIdx.x;
  float w[DTR];
  const float4* wp = (const float4*)(W_dt + (size_t)d * DTR);
#pragma unroll
  for (int i = 0; i < 8; ++i) ((float4*)w)[i] = wp[i];
  const float bb = b_dt[d];
#pragma unroll
  for (int r = 0; r < 8; ++r) {
    const float* pr = proj + (size_t)(r0 + r) * PDIM;  // wave-uniform
    float a0 = bb, a1 = 0.f, a2 = 0.f, a3 = 0.f;
#pragma unroll
    for (int k = 0; k < DTR; k += 4) {
      a0 = fmaf(pr[k + 0], w[k + 0], a0);
      a1 = fmaf(pr[k + 1], w[k + 1], a1);
      a2 = fmaf(pr[k + 2], w[k + 2], a2);
      a3 = fmaf(pr[k + 3], w[k + 3], a3);
    }
    float acc = (a0 + a1) + (a2 + a3);
    float sp = (acc > 20.f) ? acc : log1pf(__expf(acc));
    dt[(size_t)(r0 + r) * D_IN + d] = sp;
  }
}

// ---------------- pass 1: zero-init chunk run, emit {hhat,vhat,cv,sumdt} -----
__global__ __launch_bounds__(256) void k_scan1(const float* __restrict__ dt,
                                               const float* __restrict__ x,
                                               const float* __restrict__ proj,
                                               const float* __restrict__ A_log,
                                               const float* __restrict__ alpha_p,
                                               const float* __restrict__ beta_p,
                                               float* __restrict__ hh,
                                               float* __restrict__ vh,
                                               float* __restrict__ cvv,
                                               float* __restrict__ sdt) {
  const int c = blockIdx.x, b = blockIdx.z;
  const int d = blockIdx.y * 256 + threadIdx.x;
  const float alpha = alpha_p[0];
  const float beta = 1.f / (1.f + __expf(-beta_p[0]));
  float A2[D_ST];
  {
    const float4* ap = (const float4*)(A_log + (size_t)d * D_ST);
#pragma unroll
    for (int i = 0; i < 4; ++i) {
      float4 a4 = ap[i];
      A2[4 * i + 0] = -__expf(a4.x) * LOG2E;
      A2[4 * i + 1] = -__expf(a4.y) * LOG2E;
      A2[4 * i + 2] = -__expf(a4.z) * LOG2E;
      A2[4 * i + 3] = -__expf(a4.w) * LOG2E;
    }
  }
  float h[16] = {}, v[16] = {}, cv[16] = {};
  float bpow = 1.f, sd = 0.f;

  const int t0 = c * LCH;
  const float* dtp = dt + (size_t)b * LSEQ * D_IN + d;
  const float* xp = x + (size_t)b * LSEQ * D_IN + d;
  const float* bcp = proj + (size_t)b * LSEQ * PDIM + DTR;

  float dcur = dtp[(size_t)t0 * D_IN];
  float xcur = xp[(size_t)t0 * D_IN];
  float4 Bc[4];
#pragma unroll
  for (int i = 0; i < 4; ++i) Bc[i] = *(const float4*)(bcp + (size_t)t0 * PDIM + 4 * i);

  for (int j = 0; j < LCH; ++j) {
    const size_t tn = t0 + ((j + 1) & (LCH - 1));  // wraps; last prefetch unused
    float dnx = dtp[tn * D_IN];
    float xnx = xp[tn * D_IN];
    float4 Bn[4];
#pragma unroll
    for (int i = 0; i < 4; ++i) Bn[i] = *(const float4*)(bcp + tn * PDIM + 4 * i);

    sd += dcur;
    bpow *= beta;
    const float u = alpha * dcur * xcur;
    const float* Bf = (const float*)Bc;
#pragma unroll
    for (int n = 0; n < 16; ++n) {
      float a = exp2f(dcur * A2[n]);
      v[n] = fmaf(beta, v[n], u * Bf[n]);
      h[n] = fmaf(a, h[n], v[n]);
      cv[n] = fmaf(a, cv[n], bpow);
    }
    dcur = dnx; xcur = xnx;
#pragma unroll
    for (int i = 0; i < 4; ++i) Bc[i] = Bn[i];
  }

  const size_t base = ((size_t)(b * NCH + c) * D_IN + d) * D_ST;
#pragma unroll
  for (int i = 0; i < 4; ++i) {
    *(float4*)(hh + base + 4 * i) = ((float4*)h)[i];
    *(float4*)(vh + base + 4 * i) = ((float4*)v)[i];
    *(float4*)(cvv + base + 4 * i) = ((float4*)cv)[i];
  }
  sdt[(size_t)(b * NCH + c) * D_IN + d] = sd;
}

// ---------------- fixup: scan over 128 chunks; H0/V0 written in place --------
__global__ __launch_bounds__(64) void k_fix(float* __restrict__ hh,
                                            float* __restrict__ vh,
                                            const float* __restrict__ cvv,
                                            const float* __restrict__ sdt,
                                            const float* __restrict__ A_log,
                                            const float* __restrict__ beta_p) {
  const int g = blockIdx.x * 64 + threadIdx.x;  // 16384 = B * D * N
  const int b = g >> 13;
  const int dn = g & 8191;
  const float beta = 1.f / (1.f + __expf(-beta_p[0]));
  const float A2 = -__expf(A_log[dn]) * LOG2E;
  float bL = beta;
#pragma unroll
  for (int i = 0; i < 5; ++i) bL *= bL;  // beta^32

  const size_t cs = (size_t)D_IN * D_ST;  // chunk stride in state arrays
  const size_t base = (size_t)b * NCH * cs + dn;
  const size_t sbase = (size_t)b * NCH * D_IN + (dn >> 4);

  float hg[4], vg[4], cg[4], sg[4];
#pragma unroll
  for (int i = 0; i < 4; ++i) {
    hg[i] = hh[base + i * cs];
    vg[i] = vh[base + i * cs];
    cg[i] = cvv[base + i * cs];
    sg[i] = sdt[sbase + i * D_IN];
  }
  float H = 0.f, V = 0.f;
  for (int c0 = 0; c0 < NCH; c0 += 4) {
    const int cp = (c0 + 4) & (NCH - 1);  // wraps; last prefetch unused
    float hn[4], vn[4], cn[4], sn[4];
#pragma unroll
    for (int i = 0; i < 4; ++i) {
      hn[i] = hh[base + (size_t)(cp + i) * cs];
      vn[i] = vh[base + (size_t)(cp + i) * cs];
      cn[i] = cvv[base + (size_t)(cp + i) * cs];
      sn[i] = sdt[sbase + (size_t)(cp + i) * D_IN];
    }
#pragma unroll
    for (int i = 0; i < 4; ++i) {
      hh[base + (size_t)(c0 + i) * cs] = H;
      vh[base + (size_t)(c0 + i) * cs] = V;
      const float Pa = exp2f(sg[i] * A2);
      const float Hn = fmaf(Pa, H, fmaf(cg[i], V, hg[i]));
      V = fmaf(bL, V, vg[i]);
      H = Hn;
    }
#pragma unroll
    for (int i = 0; i < 4; ++i) { hg[i] = hn[i]; vg[i] = vn[i]; cg[i] = cn[i]; sg[i] = sn[i]; }
  }
}

// ---------------- pass 2: correct-init chunk run, emit y ---------------------
__global__ __launch_bounds__(256) void k_scan2(const float* __restrict__ dt,
                                               const float* __restrict__ x,
                                               const float* __restrict__ proj,
                                               const float* __restrict__ A_log,
                                               const float* __restrict__ D_param,
                                               const float* __restrict__ alpha_p,
                                               const float* __restrict__ beta_p,
                                               const float* __restrict__ hh,
                                               const float* __restrict__ vh,
                                               float* __restrict__ out) {
  const int c = blockIdx.x, b = blockIdx.z;
  const int d = blockIdx.y * 256 + threadIdx.x;
  const float alpha = alpha_p[0];
  const float beta = 1.f / (1.f + __expf(-beta_p[0]));
  const float Dv = D_param[d];
  float A2[D_ST];
  {
    const float4* ap = (const float4*)(A_log + (size_t)d * D_ST);
#pragma unroll
    for (int i = 0; i < 4; ++i) {
      float4 a4 = ap[i];
      A2[4 * i + 0] = -__expf(a4.x) * LOG2E;
      A2[4 * i + 1] = -__expf(a4.y) * LOG2E;
      A2[4 * i + 2] = -__expf(a4.z) * LOG2E;
      A2[4 * i + 3] = -__expf(a4.w) * LOG2E;
    }
  }
  const size_t ibase = ((size_t)(b * NCH + c) * D_IN + d) * D_ST;
  float h[16], v[16];
#pragma unroll
  for (int i = 0; i < 4; ++i) {
    ((float4*)h)[i] = *(const float4*)(hh + ibase + 4 * i);
    ((float4*)v)[i] = *(const float4*)(vh + ibase + 4 * i);
  }

  const int t0 = c * LCH;
  const float* dtp = dt + (size_t)b * LSEQ * D_IN + d;
  const float* xp = x + (size_t)b * LSEQ * D_IN + d;
  const float* bcp = proj + (size_t)b * LSEQ * PDIM + DTR;  // B +0..15, C +16..31
  float* op = out + (size_t)b * LSEQ * D_IN + d;

  float dcur = dtp[(size_t)t0 * D_IN];
  float xcur = xp[(size_t)t0 * D_IN];
  float4 BCc[8];
#pragma unroll
  for (int i = 0; i < 8; ++i) BCc[i] = *(const float4*)(bcp + (size_t)t0 * PDIM + 4 * i);

  for (int j = 0; j < LCH; ++j) {
    const size_t tn = t0 + ((j + 1) & (LCH - 1));
    float dnx = dtp[tn * D_IN];
    float xnx = xp[tn * D_IN];
    float4 BCn[8];
#pragma unroll
    for (int i = 0; i < 8; ++i) BCn[i] = *(const float4*)(bcp + tn * PDIM + 4 * i);

    const float u = alpha * dcur * xcur;
    const float* Bf = (const float*)BCc;  // [0:16)=B, [16:32)=C
    float y0 = 0.f, y1 = 0.f, y2 = 0.f, y3 = 0.f;
#pragma unroll
    for (int n = 0; n < 16; ++n) {
      float a = exp2f(dcur * A2[n]);
      v[n] = fmaf(beta, v[n], u * Bf[n]);
      h[n] = fmaf(a, h[n], v[n]);
      float hc = h[n] * Bf[16 + n];
      if ((n & 3) == 0) y0 += hc;
      else if ((n & 3) == 1) y1 += hc;
      else if ((n & 3) == 2) y2 += hc;
      else y3 += hc;
    }
    op[(size_t)(t0 + j) * D_IN] = (y0 + y1) + (y2 + y3) + Dv * xcur;
    dcur = dnx; xcur = xnx;
#pragma unroll
    for (int i = 0; i < 8; ++i) BCc[i] = BCn[i];
  }
}

extern "C" void kernel_launch(void* const* d_in, const int* in_sizes, int n_in,
                              void* d_out, int out_size, void* d_ws, size_t ws_size,
                              hipStream_t stream) {
  const float* x = (const float*)d_in[0];
  const float* A_log = (const float*)d_in[1];
  const float* D_param = (const float*)d_in[2];
  const float* W_xproj = (const float*)d_in[3];
  const float* W_dt = (const float*)d_in[4];
  const float* b_dt = (const float*)d_in[5];
  const float* alpha = (const float*)d_in[6];
  const float* beta_logit = (const float*)d_in[7];
  float* out = (float*)d_out;

  float* ws = (float*)d_ws;
  float* proj = ws;                                   // 524288
  float* dt = proj + (size_t)BSZ * LSEQ * PDIM;       // 4194304
  float* hh = dt + (size_t)BSZ * LSEQ * D_IN;         // 2097152
  float* vh = hh + (size_t)BSZ * NCH * D_IN * D_ST;   // 2097152
  float* cvv = vh + (size_t)BSZ * NCH * D_IN * D_ST;  // 2097152
  float* sdt = cvv + (size_t)BSZ * NCH * D_IN * D_ST; // 131072  (total 44.6 MB)

  k_proj<<<dim3(BSZ * LSEQ / 64), dim3(256), 0, stream>>>(x, W_xproj, proj);
  k_dt<<<dim3(BSZ * LSEQ / 8, D_IN / 256), dim3(256), 0, stream>>>(proj, W_dt, b_dt, dt);
  k_scan1<<<dim3(NCH, D_IN / 256, BSZ), dim3(256), 0, stream>>>(
      dt, x, proj, A_log, alpha, beta_logit, hh, vh, cvv, sdt);
  k_fix<<<dim3(BSZ * D_IN * D_ST / 64), dim3(64), 0, stream>>>(hh, vh, cvv, sdt, A_log,
                                                               beta_logit);
  k_scan2<<<dim3(NCH, D_IN / 256, BSZ), dim3(256), 0, stream>>>(
      dt, x, proj, A_log, D_param, alpha, beta_logit, hh, vh, out);
}

// Round 5
// 194.369 us; speedup vs baseline: 2.3179x; 1.3036x over previous
//
#include <hip/hip_runtime.h>

// MomentumSSM B=2, L=4096, D=512, N=16, R=32, P=64 — chunk-parallel scan, NCH=128.
// R5: k_proj = bf16x3 MFMA (hi*hi + hi*lo + lo*hi), direct global->register
// fragments, W pre-split to bf16 hi/lo by k_wprep. Scans: depth-2 prefetch via
// duplicated even/odd bodies (all register indices static — R3 spill lesson).
//
// ws layout (floats):
//   proj[b][l][p]   2 MB   (p: 0..31 dt_in, 32..47 B, 48..63 C)
//   dt  [b][l][d]  16 MB
//   hh/vh/cv [b][c][d][n]  3 x 8.4 MB  (fixup overwrites hh/vh with H0/V0 in place)
//   sdt [b][c][d]   0.5 MB
//   Whi/Wlo         64 KB each (bf16 halves of W_xproj)

#define D_IN 512
#define D_ST 16
#define DTR  32
#define BSZ  2
#define LSEQ 4096
#define PDIM 64
#define NCH  128
#define LCH  (LSEQ / NCH)  // 32
#define LOG2E 1.44269504f

typedef __attribute__((ext_vector_type(8))) short short8;
typedef __attribute__((ext_vector_type(4))) float f32x4;

__device__ inline unsigned short bf16_rne(float f) {
  unsigned b = __float_as_uint(f);
  return (unsigned short)((b + 0x7fffu + ((b >> 16) & 1u)) >> 16);
}

// split 8 fp32 into bf16 hi + bf16 lo (residual)
__device__ inline void cvt8(const float4 u, const float4 v, short8& hi, short8& lo) {
  float f[8] = {u.x, u.y, u.z, u.w, v.x, v.y, v.z, v.w};
#pragma unroll
  for (int i = 0; i < 8; ++i) {
    unsigned short h = bf16_rne(f[i]);
    hi[i] = (short)h;
    float r = f[i] - __uint_as_float((unsigned)h << 16);
    lo[i] = (short)bf16_rne(r);
  }
}

// ---------------- W -> bf16 hi/lo split (64x512 = 32768 elems) ---------------
__global__ __launch_bounds__(256) void k_wprep(const float* __restrict__ W,
                                               short* __restrict__ Whi,
                                               short* __restrict__ Wlo) {
  const int i = (blockIdx.x * 256 + threadIdx.x) * 4;
  float4 w = *(const float4*)(W + i);
  float f[4] = {w.x, w.y, w.z, w.w};
  unsigned short h[4], lo[4];
#pragma unroll
  for (int j = 0; j < 4; ++j) {
    h[j] = bf16_rne(f[j]);
    float r = f[j] - __uint_as_float((unsigned)h[j] << 16);
    lo[j] = bf16_rne(r);
  }
  *(uint2*)(Whi + i) = make_uint2(h[0] | ((unsigned)h[1] << 16), h[2] | ((unsigned)h[3] << 16));
  *(uint2*)(Wlo + i) = make_uint2(lo[0] | ((unsigned)lo[1] << 16), lo[2] | ((unsigned)lo[3] << 16));
}

// ---------------- proj = x @ W^T via MFMA bf16x3 -----------------------------
// One wave per block; 16 x-rows per wave; 4 p-tiles of 16.
// A-frag: lane l holds x[row0 + (l&15)][k0 + (l>>4)*8 + j], j=0..7
// B-frag: lane l holds W[pt*16 + (l&15)][k0 + (l>>4)*8 + j]
// C/D:    col = l&15 (p within tile), row = (l>>4)*4 + reg
#define MM3(ACC, AH, AL, BH, BL)                                        \
  ACC = __builtin_amdgcn_mfma_f32_16x16x32_bf16(AL, BH, ACC, 0, 0, 0);  \
  ACC = __builtin_amdgcn_mfma_f32_16x16x32_bf16(AH, BL, ACC, 0, 0, 0);  \
  ACC = __builtin_amdgcn_mfma_f32_16x16x32_bf16(AH, BH, ACC, 0, 0, 0);

#define LOADB(P, S)                                   \
  {                                                   \
    const int kb = ((S) & 15) * 32;                   \
    P##h0 = *(const short8*)(bh + kb);                \
    P##h1 = *(const short8*)(bh + 8192 + kb);         \
    P##h2 = *(const short8*)(bh + 16384 + kb);        \
    P##h3 = *(const short8*)(bh + 24576 + kb);        \
    P##l0 = *(const short8*)(bl + kb);                \
    P##l1 = *(const short8*)(bl + 8192 + kb);         \
    P##l2 = *(const short8*)(bl + 16384 + kb);        \
    P##l3 = *(const short8*)(bl + 24576 + kb);        \
  }

#define LOADA(Aa, Ab, S)                              \
  {                                                   \
    const int ka = ((S) & 15) * 32;                   \
    Aa = *(const float4*)(xr + ka);                   \
    Ab = *(const float4*)(xr + ka + 4);               \
  }

#define SUBSTEP(Aa, Ab, P, SA, SB)                    \
  {                                                   \
    short8 ahi, alo;                                  \
    cvt8(Aa, Ab, ahi, alo);                           \
    MM3(acc0, ahi, alo, P##h0, P##l0);                \
    MM3(acc1, ahi, alo, P##h1, P##l1);                \
    MM3(acc2, ahi, alo, P##h2, P##l2);                \
    MM3(acc3, ahi, alo, P##h3, P##l3);                \
    LOADB(P, SB);                                     \
    LOADA(Aa, Ab, SA);                                \
  }

__global__ __launch_bounds__(64) void k_proj(const float* __restrict__ x,
                                             const short* __restrict__ Whi,
                                             const short* __restrict__ Wlo,
                                             float* __restrict__ proj) {
  const int row0 = blockIdx.x * 16;
  const int l = threadIdx.x;
  const int m = l & 15;
  const int ko = (l >> 4) * 8;
  const float* xr = x + (size_t)(row0 + m) * D_IN + ko;
  const short* bh = Whi + (size_t)m * D_IN + ko;
  const short* bl = Wlo + (size_t)m * D_IN + ko;

  f32x4 acc0 = {0.f, 0.f, 0.f, 0.f}, acc1 = acc0, acc2 = acc0, acc3 = acc0;
  float4 A0a, A0b, A1a, A1b, A2a, A2b, A3a, A3b;
  short8 Xh0, Xh1, Xh2, Xh3, Xl0, Xl1, Xl2, Xl3;
  short8 Yh0, Yh1, Yh2, Yh3, Yl0, Yl1, Yl2, Yl3;
  LOADA(A0a, A0b, 0); LOADA(A1a, A1b, 1); LOADA(A2a, A2b, 2); LOADA(A3a, A3b, 3);
  LOADB(X, 0); LOADB(Y, 1);

#pragma unroll
  for (int it = 0; it < 4; ++it) {
    const int s = it * 4;
    SUBSTEP(A0a, A0b, X, s + 4, s + 2);
    SUBSTEP(A1a, A1b, Y, s + 5, s + 3);
    SUBSTEP(A2a, A2b, X, s + 6, s + 4);
    SUBSTEP(A3a, A3b, Y, s + 7, s + 5);
  }

  const int col = l & 15;
  const int r0 = (l >> 4) * 4;
#pragma unroll
  for (int r = 0; r < 4; ++r) {
    float* pr = proj + (size_t)(row0 + r0 + r) * PDIM + col;
    pr[0] = acc0[r]; pr[16] = acc1[r]; pr[32] = acc2[r]; pr[48] = acc3[r];
  }
}

// ---------------- dt = softplus(proj[:, :32] @ W_dt^T + b_dt) ----------------
__global__ __launch_bounds__(256) void k_dt(const float* __restrict__ proj,
                                            const float* __restrict__ W_dt,
                                            const float* __restrict__ b_dt,
                                            float* __restrict__ dt) {
  const int r0 = blockIdx.x * 8;
  const int d = blockIdx.y * 256 + threadIdx.x;
  float w[DTR];
  const float4* wp = (const float4*)(W_dt + (size_t)d * DTR);
#pragma unroll
  for (int i = 0; i < 8; ++i) ((float4*)w)[i] = wp[i];
  const float bb = b_dt[d];
#pragma unroll
  for (int r = 0; r < 8; ++r) {
    const float* pr = proj + (size_t)(r0 + r) * PDIM;  // wave-uniform
    float a0 = bb, a1 = 0.f, a2 = 0.f, a3 = 0.f;
#pragma unroll
    for (int k = 0; k < DTR; k += 4) {
      a0 = fmaf(pr[k + 0], w[k + 0], a0);
      a1 = fmaf(pr[k + 1], w[k + 1], a1);
      a2 = fmaf(pr[k + 2], w[k + 2], a2);
      a3 = fmaf(pr[k + 3], w[k + 3], a3);
    }
    float acc = (a0 + a1) + (a2 + a3);
    float sp = (acc > 20.f) ? acc : log1pf(__expf(acc));
    dt[(size_t)(r0 + r) * D_IN + d] = sp;
  }
}

// ---------------- pass 1: zero-init chunk run, emit {hhat,vhat,cv,sumdt} -----
#define S1_STEP(DC, XC, BC)                     \
  {                                             \
    sd += DC;                                   \
    bpow *= beta;                               \
    const float u = alpha * DC * XC;            \
    const float* Bf = (const float*)BC;         \
    _Pragma("unroll")                           \
    for (int n = 0; n < 16; ++n) {              \
      float a = exp2f(DC * A2[n]);              \
      v[n] = fmaf(beta, v[n], u * Bf[n]);       \
      h[n] = fmaf(a, h[n], v[n]);               \
      cv[n] = fmaf(a, cv[n], bpow);             \
    }                                           \
  }

__global__ __launch_bounds__(256) void k_scan1(const float* __restrict__ dt,
                                               const float* __restrict__ x,
                                               const float* __restrict__ proj,
                                               const float* __restrict__ A_log,
                                               const float* __restrict__ alpha_p,
                                               const float* __restrict__ beta_p,
                                               float* __restrict__ hh,
                                               float* __restrict__ vh,
                                               float* __restrict__ cvv,
                                               float* __restrict__ sdt) {
  const int c = blockIdx.x, b = blockIdx.z;
  const int d = blockIdx.y * 256 + threadIdx.x;
  const float alpha = alpha_p[0];
  const float beta = 1.f / (1.f + __expf(-beta_p[0]));
  float A2[D_ST];
  {
    const float4* ap = (const float4*)(A_log + (size_t)d * D_ST);
#pragma unroll
    for (int i = 0; i < 4; ++i) {
      float4 a4 = ap[i];
      A2[4 * i + 0] = -__expf(a4.x) * LOG2E;
      A2[4 * i + 1] = -__expf(a4.y) * LOG2E;
      A2[4 * i + 2] = -__expf(a4.z) * LOG2E;
      A2[4 * i + 3] = -__expf(a4.w) * LOG2E;
    }
  }
  float h[16] = {}, v[16] = {}, cv[16] = {};
  float bpow = 1.f, sd = 0.f;

  const int t0 = c * LCH;
  const float* dtp = dt + (size_t)b * LSEQ * D_IN + d;
  const float* xp = x + (size_t)b * LSEQ * D_IN + d;
  const float* bcp = proj + (size_t)b * LSEQ * PDIM + DTR;

  float d0 = dtp[(size_t)t0 * D_IN], x0v = xp[(size_t)t0 * D_IN];
  float d1 = dtp[(size_t)(t0 + 1) * D_IN], x1v = xp[(size_t)(t0 + 1) * D_IN];
  float4 B0[4], B1[4];
#pragma unroll
  for (int i = 0; i < 4; ++i) {
    B0[i] = *(const float4*)(bcp + (size_t)t0 * PDIM + 4 * i);
    B1[i] = *(const float4*)(bcp + (size_t)(t0 + 1) * PDIM + 4 * i);
  }

  for (int j = 0; j < LCH; j += 2) {
    const size_t ta = t0 + ((j + 2) & (LCH - 1));  // wraps; tail prefetch unused
    S1_STEP(d0, x0v, B0);
    d0 = dtp[ta * D_IN]; x0v = xp[ta * D_IN];
#pragma unroll
    for (int i = 0; i < 4; ++i) B0[i] = *(const float4*)(bcp + ta * PDIM + 4 * i);

    const size_t tb = t0 + ((j + 3) & (LCH - 1));
    S1_STEP(d1, x1v, B1);
    d1 = dtp[tb * D_IN]; x1v = xp[tb * D_IN];
#pragma unroll
    for (int i = 0; i < 4; ++i) B1[i] = *(const float4*)(bcp + tb * PDIM + 4 * i);
  }

  const size_t base = ((size_t)(b * NCH + c) * D_IN + d) * D_ST;
#pragma unroll
  for (int i = 0; i < 4; ++i) {
    *(float4*)(hh + base + 4 * i) = ((float4*)h)[i];
    *(float4*)(vh + base + 4 * i) = ((float4*)v)[i];
    *(float4*)(cvv + base + 4 * i) = ((float4*)cv)[i];
  }
  sdt[(size_t)(b * NCH + c) * D_IN + d] = sd;
}

// ---------------- fixup: scan over 128 chunks; H0/V0 written in place --------
__global__ __launch_bounds__(64) void k_fix(float* __restrict__ hh,
                                            float* __restrict__ vh,
                                            const float* __restrict__ cvv,
                                            const float* __restrict__ sdt,
                                            const float* __restrict__ A_log,
                                            const float* __restrict__ beta_p) {
  const int g = blockIdx.x * 64 + threadIdx.x;  // 16384 = B * D * N
  const int b = g >> 13;
  const int dn = g & 8191;
  const float beta = 1.f / (1.f + __expf(-beta_p[0]));
  const float A2 = -__expf(A_log[dn]) * LOG2E;
  float bL = beta;
#pragma unroll
  for (int i = 0; i < 5; ++i) bL *= bL;  // beta^32

  const size_t cs = (size_t)D_IN * D_ST;
  const size_t base = (size_t)b * NCH * cs + dn;
  const size_t sbase = (size_t)b * NCH * D_IN + (dn >> 4);

  float hg[4], vg[4], cg[4], sg[4];
#pragma unroll
  for (int i = 0; i < 4; ++i) {
    hg[i] = hh[base + i * cs];
    vg[i] = vh[base + i * cs];
    cg[i] = cvv[base + i * cs];
    sg[i] = sdt[sbase + i * D_IN];
  }
  float H = 0.f, V = 0.f;
  for (int c0 = 0; c0 < NCH; c0 += 4) {
    const int cp = (c0 + 4) & (NCH - 1);
    float hn[4], vn[4], cn[4], sn[4];
#pragma unroll
    for (int i = 0; i < 4; ++i) {
      hn[i] = hh[base + (size_t)(cp + i) * cs];
      vn[i] = vh[base + (size_t)(cp + i) * cs];
      cn[i] = cvv[base + (size_t)(cp + i) * cs];
      sn[i] = sdt[sbase + (size_t)(cp + i) * D_IN];
    }
#pragma unroll
    for (int i = 0; i < 4; ++i) {
      hh[base + (size_t)(c0 + i) * cs] = H;
      vh[base + (size_t)(c0 + i) * cs] = V;
      const float Pa = exp2f(sg[i] * A2);
      const float Hn = fmaf(Pa, H, fmaf(cg[i], V, hg[i]));
      V = fmaf(bL, V, vg[i]);
      H = Hn;
    }
#pragma unroll
    for (int i = 0; i < 4; ++i) { hg[i] = hn[i]; vg[i] = vn[i]; cg[i] = cn[i]; sg[i] = sn[i]; }
  }
}

// ---------------- pass 2: correct-init chunk run, emit y ---------------------
#define S2_STEP(DC, XC, BC, TT)                                   \
  {                                                               \
    const float u = alpha * DC * XC;                              \
    const float* Bf = (const float*)BC;                           \
    float y0 = 0.f, y1 = 0.f, y2 = 0.f, y3 = 0.f;                 \
    _Pragma("unroll")                                             \
    for (int n = 0; n < 16; ++n) {                                \
      float a = exp2f(DC * A2[n]);                                \
      v[n] = fmaf(beta, v[n], u * Bf[n]);                         \
      h[n] = fmaf(a, h[n], v[n]);                                 \
      float hc = h[n] * Bf[16 + n];                               \
      if ((n & 3) == 0) y0 += hc;                                 \
      else if ((n & 3) == 1) y1 += hc;                            \
      else if ((n & 3) == 2) y2 += hc;                            \
      else y3 += hc;                                              \
    }                                                             \
    op[(size_t)(TT) * D_IN] = (y0 + y1) + (y2 + y3) + Dv * XC;    \
  }

__global__ __launch_bounds__(256) void k_scan2(const float* __restrict__ dt,
                                               const float* __restrict__ x,
                                               const float* __restrict__ proj,
                                               const float* __restrict__ A_log,
                                               const float* __restrict__ D_param,
                                               const float* __restrict__ alpha_p,
                                               const float* __restrict__ beta_p,
                                               const float* __restrict__ hh,
                                               const float* __restrict__ vh,
                                               float* __restrict__ out) {
  const int c = blockIdx.x, b = blockIdx.z;
  const int d = blockIdx.y * 256 + threadIdx.x;
  const float alpha = alpha_p[0];
  const float beta = 1.f / (1.f + __expf(-beta_p[0]));
  const float Dv = D_param[d];
  float A2[D_ST];
  {
    const float4* ap = (const float4*)(A_log + (size_t)d * D_ST);
#pragma unroll
    for (int i = 0; i < 4; ++i) {
      float4 a4 = ap[i];
      A2[4 * i + 0] = -__expf(a4.x) * LOG2E;
      A2[4 * i + 1] = -__expf(a4.y) * LOG2E;
      A2[4 * i + 2] = -__expf(a4.z) * LOG2E;
      A2[4 * i + 3] = -__expf(a4.w) * LOG2E;
    }
  }
  const size_t ibase = ((size_t)(b * NCH + c) * D_IN + d) * D_ST;
  float h[16], v[16];
#pragma unroll
  for (int i = 0; i < 4; ++i) {
    ((float4*)h)[i] = *(const float4*)(hh + ibase + 4 * i);
    ((float4*)v)[i] = *(const float4*)(vh + ibase + 4 * i);
  }

  const int t0 = c * LCH;
  const float* dtp = dt + (size_t)b * LSEQ * D_IN + d;
  const float* xp = x + (size_t)b * LSEQ * D_IN + d;
  const float* bcp = proj + (size_t)b * LSEQ * PDIM + DTR;  // B +0..15, C +16..31
  float* op = out + (size_t)b * LSEQ * D_IN + d;

  float d0 = dtp[(size_t)t0 * D_IN], x0v = xp[(size_t)t0 * D_IN];
  float d1 = dtp[(size_t)(t0 + 1) * D_IN], x1v = xp[(size_t)(t0 + 1) * D_IN];
  float4 BC0[8], BC1[8];
#pragma unroll
  for (int i = 0; i < 8; ++i) {
    BC0[i] = *(const float4*)(bcp + (size_t)t0 * PDIM + 4 * i);
    BC1[i] = *(const float4*)(bcp + (size_t)(t0 + 1) * PDIM + 4 * i);
  }

  for (int j = 0; j < LCH; j += 2) {
    const size_t ta = t0 + ((j + 2) & (LCH - 1));
    S2_STEP(d0, x0v, BC0, t0 + j);
    d0 = dtp[ta * D_IN]; x0v = xp[ta * D_IN];
#pragma unroll
    for (int i = 0; i < 8; ++i) BC0[i] = *(const float4*)(bcp + ta * PDIM + 4 * i);

    const size_t tb = t0 + ((j + 3) & (LCH - 1));
    S2_STEP(d1, x1v, BC1, t0 + j + 1);
    d1 = dtp[tb * D_IN]; x1v = xp[tb * D_IN];
#pragma unroll
    for (int i = 0; i < 8; ++i) BC1[i] = *(const float4*)(bcp + tb * PDIM + 4 * i);
  }
}

extern "C" void kernel_launch(void* const* d_in, const int* in_sizes, int n_in,
                              void* d_out, int out_size, void* d_ws, size_t ws_size,
                              hipStream_t stream) {
  const float* x = (const float*)d_in[0];
  const float* A_log = (const float*)d_in[1];
  const float* D_param = (const float*)d_in[2];
  const float* W_xproj = (const float*)d_in[3];
  const float* W_dt = (const float*)d_in[4];
  const float* b_dt = (const float*)d_in[5];
  const float* alpha = (const float*)d_in[6];
  const float* beta_logit = (const float*)d_in[7];
  float* out = (float*)d_out;

  float* ws = (float*)d_ws;
  float* proj = ws;                                   // 524288
  float* dt = proj + (size_t)BSZ * LSEQ * PDIM;       // 4194304
  float* hh = dt + (size_t)BSZ * LSEQ * D_IN;         // 2097152
  float* vh = hh + (size_t)BSZ * NCH * D_IN * D_ST;   // 2097152
  float* cvv = vh + (size_t)BSZ * NCH * D_IN * D_ST;  // 2097152
  float* sdt = cvv + (size_t)BSZ * NCH * D_IN * D_ST; // 131072
  short* Whi = (short*)(sdt + (size_t)BSZ * NCH * D_IN);  // 32768 shorts
  short* Wlo = Whi + (size_t)PDIM * D_IN;                 // 32768 shorts

  k_wprep<<<dim3(PDIM * D_IN / 1024), dim3(256), 0, stream>>>(W_xproj, Whi, Wlo);
  k_proj<<<dim3(BSZ * LSEQ / 16), dim3(64), 0, stream>>>(x, Whi, Wlo, proj);
  k_dt<<<dim3(BSZ * LSEQ / 8, D_IN / 256), dim3(256), 0, stream>>>(proj, W_dt, b_dt, dt);
  k_scan1<<<dim3(NCH, D_IN / 256, BSZ), dim3(256), 0, stream>>>(
      dt, x, proj, A_log, alpha, beta_logit, hh, vh, cvv, sdt);
  k_fix<<<dim3(BSZ * D_IN * D_ST / 64), dim3(64), 0, stream>>>(hh, vh, cvv, sdt, A_log,
                                                               beta_logit);
  k_scan2<<<dim3(NCH, D_IN / 256, BSZ), dim3(256), 0, stream>>>(
      dt, x, proj, A_log, D_param, alpha, beta_logit, hh, vh, out);
}